// Round 20
// baseline (253.123 us; speedup 1.0000x reference)
//
#include <hip/hip_runtime.h>
#include <hip/hip_bf16.h>

#define NROW_F 8192
#define NROW_B 65536
#define KDIM   384
#define BM 128
#define BN 128
#define NSUB 16
#define NGRP (NROW_B / (BN * NSUB))      // 32
#define NBM  (NROW_F / BM)               // 64
#define NWG  (NBM * NGRP)                // 2048

// LDS (80 KB -> 2 blocks/CU):
//   [0,48K)  A staging (prologue only). After A->regs the region is dead:
//            sB slice [0,8K); epilogue red[] [16K,17K); B bufs 4,5 [24K,40K).
//   [48K,80K) B bufs 0..3.
#define LDSS2 0
#define LDSR2 16384
#define BBASE(i) ((i) < 4 ? 49152 + 8192 * (i) : 24576 + 8192 * ((i) - 4))
#define LDS_TOT 81920

typedef int   i32x4 __attribute__((ext_vector_type(4)));
typedef float f32x4 __attribute__((ext_vector_type(4)));

static __device__ __forceinline__ void stage16(const void* g, void* l) {
  __builtin_amdgcn_global_load_lds(
      (const __attribute__((address_space(1))) unsigned int*)g,
      (__attribute__((address_space(3))) unsigned int*)l, 16, 0, 0);
}

// ---------------------------------------------------------------------------
// 1) L2-normalize rows + symmetric i8 quantization with per-row scale.
// ---------------------------------------------------------------------------
__global__ __launch_bounds__(256) void quantize_rows_kernel(
    const float* __restrict__ in, char* __restrict__ out8,
    float* __restrict__ scales, int nrows) {
  int row = blockIdx.x * 8 + (threadIdx.x >> 5);
  int l   = threadIdx.x & 31;
  if (row >= nrows) return;
  const f32x4* r = (const f32x4*)(in + (size_t)row * KDIM);
  f32x4 v[3];
  float ss = 0.f, mx = 0.f;
#pragma unroll
  for (int i = 0; i < 3; ++i) {
    v[i] = r[l + i * 32];
#pragma unroll
    for (int j = 0; j < 4; ++j) {
      ss += v[i][j] * v[i][j];
      mx = fmaxf(mx, fabsf(v[i][j]));
    }
  }
#pragma unroll
  for (int d = 1; d < 32; d <<= 1) {
    ss += __shfl_xor(ss, d, 64);
    mx = fmaxf(mx, __shfl_xor(mx, d, 64));
  }
  mx = fmaxf(mx, 1e-30f);
  float inv = rsqrtf(fmaxf(ss, 1e-24f));
  float scl = 127.0f / mx;
  if (l == 0) scales[row] = mx * inv * (1.0f / 127.0f);
  char* o = out8 + (size_t)row * KDIM;
#pragma unroll
  for (int i = 0; i < 3; ++i) {
    char4 c;
    c.x = (char)__float2int_rn(v[i][0] * scl);
    c.y = (char)__float2int_rn(v[i][1] * scl);
    c.z = (char)__float2int_rn(v[i][2] * scl);
    c.w = (char)__float2int_rn(v[i][3] * scl);
    *(char4*)(o + (l + i * 32) * 4) = c;
  }
}

// ---------------------------------------------------------------------------
// 2) maxsim: i8 MFMA 16x16x64, A in regs, K=128 PER PHASE (2 k6-tiles per
//    barrier): 48 phases instead of 96 halves all sync costs (r19 audit:
//    ~45% of slot time was vmcnt+barrier+lgkm+skew). B six-buffered (bufs
//    4,5 live in the dead A region) -> stage distance 2 phases, uniform
//    vmcnt(4). Buf cycle period = 3 phases, subtile-uniform:
//      ph0: compute bufs(0,1), reg-read (2,3), stage->bufs(0,1)
//      ph1: compute (2,3), read (4,5), stage->(2,3)
//      ph2: compute (4,5), read (0,1)[next sub], stage->(4,5)
//    Reg ping-pong period = 2 subtiles -> 6-phase unroll.
// ---------------------------------------------------------------------------
__global__ __launch_bounds__(256, 2) void maxsim_kernel(
    const char* __restrict__ F8,    // 8192 x 384 i8
    const char* __restrict__ B8,    // 65536 x 384 i8
    const float* __restrict__ sA,   // 8192
    const float* __restrict__ sB,   // 65536
    float* __restrict__ partial) {  // NGRP x 8192 (max sim)
  __shared__ __align__(16) char smem[LDS_TOT];

  const int tid  = threadIdx.x;
  const int wv   = tid >> 6;         // 0..3
  const int lane = tid & 63;
  const int l15  = lane & 15;
  const int lhi  = lane >> 4;
  const int wr   = wv >> 1;          // 0..1 (row half)
  const int wc   = wv & 1;           // 0..1 (col half)

  const int wg  = (blockIdx.x & 7) * (NWG / 8) + (blockIdx.x >> 3);
  const int bm  = wg & (NBM - 1);
  const int grp = wg >> 6;
  const size_t brow = (size_t)bm * BM;

  const int srow = tid >> 2;                           // 0..63
  const int gsw  = (tid & 3) ^ ((tid >> 3) & 3);       // inverse write swizzle

  // ---- prologue step 1: stage A (12 issues), drain, A -> registers ----
  {
    const char* gA = F8 + (size_t)(brow + srow) * KDIM + gsw * 16;
    char* lA = smem + wv * 1024;
#pragma unroll
    for (int kt = 0; kt < 6; ++kt) {
      stage16(gA + kt * 64,             lA + kt * 8192);
      stage16(gA + kt * 64 + 64 * KDIM, lA + kt * 8192 + 4096);
    }
  }
  asm volatile("s_waitcnt vmcnt(0)" ::: "memory");
  __builtin_amdgcn_s_barrier();

  const int cof = ((l15 >> 1) & 3) << 4;
  auto ldA8 = [&](int k6, int m) -> i32x4 {
    int byte = k6 * 8192 + (wr * 64 + m * 16 + l15) * 64 + ((lhi << 4) ^ cof);
    return *reinterpret_cast<const i32x4*>(smem + byte);
  };
  i32x4 a[6][4];
#pragma unroll
  for (int k6 = 0; k6 < 6; ++k6)
#pragma unroll
    for (int m = 0; m < 4; ++m) a[k6][m] = ldA8(k6, m);
  asm volatile("s_waitcnt lgkmcnt(0)" ::: "memory");
  __builtin_amdgcn_s_barrier();   // ALL waves done reading A region

  // ---- prologue step 2: sB into dead A region, then tiles 0..5 ----
  {
    const char* gs = (const char*)(sB + (size_t)grp * 2048) + tid * 16;
    stage16(gs,        smem + LDSS2 + wv * 1024);
    stage16(gs + 4096, smem + LDSS2 + 4096 + wv * 1024);
  }
  auto stageB = [&](int s2, int koff, int base) {
    const char* g = B8 + ((size_t)grp * 2048 + s2 * 128 + srow) * KDIM
                    + koff * 64 + gsw * 16;
    char* l = smem + base + wv * 1024;
    stage16(g, l);
    stage16(g + (size_t)64 * KDIM, l + 4096);
  };
#pragma unroll
  for (int k = 0; k < 6; ++k) ;  // (placeholder keeps clang quiet)
  stageB(0, 0, BBASE(0));
  stageB(0, 1, BBASE(1));
  stageB(0, 2, BBASE(2));
  stageB(0, 3, BBASE(3));
  stageB(0, 4, BBASE(4));
  stageB(0, 5, BBASE(5));

  auto ldB8 = [&](int base, int n) -> i32x4 {
    int byte = base + (wc * 64 + n * 16 + l15) * 64 + ((lhi << 4) ^ cof);
    return *reinterpret_cast<const i32x4*>(smem + byte);
  };

  i32x4 acc[4][4];
  f32x4 vm[4];
#pragma unroll
  for (int m = 0; m < 4; ++m) {
    vm[m] = f32x4{-1e30f, -1e30f, -1e30f, -1e30f};
#pragma unroll
    for (int n = 0; n < 4; ++n) acc[m][n] = i32x4{0, 0, 0, 0};
  }

  // outstanding: sB(2) + t0..t5(12) = 14; vmcnt(8) retires sB,t0,t1.
  asm volatile("s_waitcnt vmcnt(8)" ::: "memory");
  __builtin_amdgcn_s_barrier();

  i32x4 bP[4], bQ[4], bR[4], bS[4];
#pragma unroll
  for (int n = 0; n < 4; ++n) bP[n] = ldB8(BBASE(0), n);
#pragma unroll
  for (int n = 0; n < 4; ++n) bQ[n] = ldB8(BBASE(1), n);
  asm volatile("s_waitcnt lgkmcnt(0)" ::: "memory");
  // entering loop: outstanding = t2..t5 = 8 issues.

// Phase PH (0,1,2) of subtile SUBX: compute tiles k6=(2PH,2PH+1) from
// (CA,CB); reg-read bufs ((2PH+2)%6,(2PH+3)%6) into (NA,NB); stage next
// subtile's koffs (2PH,2PH+1) into bufs (2PH,2PH+1).
#define PHASE(PH, SUBX, CA, CB, NA, NB) do {                                  \
    asm volatile("s_waitcnt vmcnt(4)" ::: "memory");                          \
    __builtin_amdgcn_s_barrier();                                             \
    __builtin_amdgcn_sched_barrier(0);                                        \
    _Pragma("unroll")                                                         \
    for (int n = 0; n < 4; ++n) NA[n] = ldB8(BBASE((2 * (PH) + 2) % 6), n);   \
    _Pragma("unroll")                                                         \
    for (int n = 0; n < 4; ++n) NB[n] = ldB8(BBASE((2 * (PH) + 3) % 6), n);   \
    stageB(((SUBX) + 1) & (NSUB - 1), 2 * (PH),     BBASE(2 * (PH)));         \
    stageB(((SUBX) + 1) & (NSUB - 1), 2 * (PH) + 1, BBASE(2 * (PH) + 1));     \
    __builtin_amdgcn_sched_barrier(0);                                        \
    __builtin_amdgcn_s_setprio(1);                                            \
    _Pragma("unroll")                                                         \
    for (int n = 0; n < 4; ++n)                                               \
      _Pragma("unroll")                                                       \
      for (int m = 0; m < 4; ++m)                                             \
        acc[m][n] = __builtin_amdgcn_mfma_i32_16x16x64_i8(                    \
            a[2 * (PH)][m], CA[n], acc[m][n], 0, 0, 0);                       \
    _Pragma("unroll")                                                         \
    for (int n = 0; n < 4; ++n)                                               \
      _Pragma("unroll")                                                       \
      for (int m = 0; m < 4; ++m)                                             \
        acc[m][n] = __builtin_amdgcn_mfma_i32_16x16x64_i8(                    \
            a[2 * (PH) + 1][m], CB[n], acc[m][n], 0, 0, 0);                   \
    __builtin_amdgcn_s_setprio(0);                                            \
    asm volatile("s_waitcnt lgkmcnt(0)" ::: "memory");                        \
    __builtin_amdgcn_sched_barrier(0);                                        \
  } while (0)

#define FOLD(S) do {                                                          \
    float sb[4];                                                              \
    _Pragma("unroll")                                                         \
    for (int n = 0; n < 4; ++n)                                               \
      sb[n] = *reinterpret_cast<const float*>(                                \
          smem + LDSS2 + ((S) * 128 + wc * 64 + n * 16 + l15) * 4);           \
    _Pragma("unroll")                                                         \
    for (int m = 0; m < 4; ++m) {                                             \
      _Pragma("unroll")                                                       \
      for (int n = 0; n < 4; ++n)                                             \
        _Pragma("unroll")                                                     \
        for (int j = 0; j < 4; ++j)                                           \
          vm[m][j] = fmaxf(vm[m][j], (float)acc[m][n][j] * sb[n]);            \
      _Pragma("unroll")                                                       \
      for (int n = 0; n < 4; ++n) acc[m][n] = i32x4{0, 0, 0, 0};              \
    }                                                                         \
  } while (0)

  for (int sub = 0; sub < NSUB; sub += 2) {
    PHASE(0, sub, bP, bQ, bR, bS);
    PHASE(1, sub, bR, bS, bP, bQ);
    PHASE(2, sub, bP, bQ, bR, bS);
    FOLD(sub);
    PHASE(0, sub + 1, bR, bS, bP, bQ);
    PHASE(1, sub + 1, bP, bQ, bR, bS);
    PHASE(2, sub + 1, bR, bS, bP, bQ);
    FOLD(sub + 1);
  }
#undef PHASE
#undef FOLD

  // ---- epilogue ----
  asm volatile("s_waitcnt vmcnt(0)" ::: "memory");
#pragma unroll
  for (int d = 1; d < 16; d <<= 1)
#pragma unroll
    for (int m = 0; m < 4; ++m)
#pragma unroll
      for (int j = 0; j < 4; ++j)
        vm[m][j] = fmaxf(vm[m][j], __shfl_xor(vm[m][j], d, 64));

  float* red = (float*)(smem + LDSR2);
  __syncthreads();
  if (l15 == 0) {
#pragma unroll
    for (int m = 0; m < 4; ++m)
#pragma unroll
      for (int j = 0; j < 4; ++j)
        red[wc * 128 + wr * 64 + m * 16 + lhi * 4 + j] = vm[m][j];
  }
  __syncthreads();
  if (tid < BM) {
    float x = fmaxf(red[tid], red[128 + tid]);
    partial[(size_t)grp * NROW_F + brow + tid] = x * sA[brow + tid];
  }
}

// ---------------------------------------------------------------------------
// 3) combine (blocks 0..31) + build W (blocks 32..87) fused (r19 tail).
// ---------------------------------------------------------------------------
__global__ __launch_bounds__(256) void combw_kernel(
    const float* __restrict__ partial, float* __restrict__ md,
    float* __restrict__ W) {
  if (blockIdx.x < 32) {
    int r = blockIdx.x * 256 + threadIdx.x;
    float m = -1e30f;
#pragma unroll
    for (int c = 0; c < NGRP; ++c) m = fmaxf(m, partial[(size_t)c * NROW_F + r]);
    float d = 1.0f - m;
    md[r] = fminf(fmaxf(d, 0.0f), 2.0f);
    return;
  }
  int idx = (blockIdx.x - 32) * 256 + threadIdx.x;   // < 448*32 = 14336
  int y = idx >> 5, g = idx & 31;
  float ksum = 0.f, acc = 0.f;
#pragma unroll
  for (int t = -16; t <= 16; ++t) {
    float ft = (float)t * 0.25f;
    float kv = expf(-0.5f * ft * ft);
    ksum += kv;
    int p = y + t;
    p = (p < 0) ? -p : ((p > 447) ? 894 - p : p);
    float src = ((float)p + 0.5f) * (1.0f / 14.0f) - 0.5f;
    float fl = floorf(src);
    int i0 = (int)fl;
    float fr = src - fl;
    int c0 = i0 < 0 ? 0 : (i0 > 31 ? 31 : i0);
    int i1 = i0 + 1;
    int c1 = i1 < 0 ? 0 : (i1 > 31 ? 31 : i1);
    float w = 0.f;
    if (c0 == g) w += 1.0f - fr;
    if (c1 == g) w += fr;
    acc += kv * w;
  }
  W[idx] = acc / ksum;
}

// ---------------------------------------------------------------------------
// 4) top-10 mean per batch (r19 tail): 1 wave, register-resident, shuffles.
// ---------------------------------------------------------------------------
__global__ __launch_bounds__(64) void topk_kernel(
    const float* __restrict__ partial, float* __restrict__ out) {
  int b = blockIdx.x, lane = threadIdx.x;
  float vals[16];
#pragma unroll
  for (int k = 0; k < 16; ++k) {
    int r = b * 1024 + k * 64 + lane;
    float m = -1e30f;
#pragma unroll
    for (int c = 0; c < NGRP; ++c) m = fmaxf(m, partial[(size_t)c * NROW_F + r]);
    float d = 1.0f - m;
    vals[k] = fminf(fmaxf(d, 0.0f), 2.0f);
  }
  float total = 0.f;
  for (int it = 0; it < 10; ++it) {
    float lb = vals[0]; int li = 0;
#pragma unroll
    for (int k = 1; k < 16; ++k)
      if (vals[k] > lb) { lb = vals[k]; li = k; }
    float wm = lb;
#pragma unroll
    for (int d = 1; d < 64; d <<= 1) wm = fmaxf(wm, __shfl_xor(wm, d, 64));
    unsigned long long mask = __ballot(lb == wm);
    int winner = (int)(__ffsll(mask) - 1);
    bool kill = (lane == winner);
#pragma unroll
    for (int k = 0; k < 16; ++k)
      vals[k] = (kill && k == li) ? -1e30f : vals[k];
    total += wm;
  }
  if (lane == 0) out[b] = total * 0.1f;
}

// ---------------------------------------------------------------------------
// 5) anomaly_map = W · md_grid · W^T, one block per (b, y) (r19 tail).
// ---------------------------------------------------------------------------
__global__ __launch_bounds__(256) void map_kernel(
    const float* __restrict__ md, const float* __restrict__ W,
    float* __restrict__ out) {  // 8 x 448 x 448
  __shared__ float tmpv[32];
  int y = blockIdx.x % 448;
  int b = blockIdx.x / 448;
  int tid = threadIdx.x;
  if (tid < 32) {
    const float* w = W + y * 32;
    const float* m = md + b * 1024 + tid;
    float s = 0.f;
#pragma unroll
    for (int gy = 0; gy < 32; ++gy) s += w[gy] * m[gy * 32];
    tmpv[tid] = s;
  }
  __syncthreads();
  for (int x = tid; x < 448; x += 256) {
    const float* w = W + x * 32;
    float s = 0.f;
#pragma unroll
    for (int gx = 0; gx < 32; ++gx) s += w[gx] * tmpv[gx];
    out[(size_t)blockIdx.x * 448 + x] = s;
  }
}

// ---------------------------------------------------------------------------
extern "C" void kernel_launch(void* const* d_in, const int* in_sizes, int n_in,
                              void* d_out, int out_size, void* d_ws, size_t ws_size,
                              hipStream_t stream) {
  const float* features = (const float*)d_in[0];   // 8*1024*384
  const float* bank     = (const float*)d_in[1];   // 65536*384
  float* out = (float*)d_out;                      // [8 scores][8*448*448 map]

  char* ws = (char*)d_ws;
  char*  mb8     = ws;                              // 25,165,824 B
  char*  f8      = ws + 25165824;                   //  3,145,728 B
  float* sB      = (float*)(ws + 28311552);         //    262,144 B
  float* sA      = (float*)(ws + 28573696);         //     32,768 B
  float* partial = (float*)(ws + 28606464);         //  1,048,576 B
  float* md      = (float*)(ws + 29655040);         //     32,768 B
  float* W       = (float*)(ws + 29687808);         //     57,344 B

  quantize_rows_kernel<<<NROW_B / 8, 256, 0, stream>>>(bank, mb8, sB, NROW_B);
  quantize_rows_kernel<<<NROW_F / 8, 256, 0, stream>>>(features, f8, sA, NROW_F);
  maxsim_kernel<<<NWG, 256, 0, stream>>>(f8, mb8, sA, sB, partial);
  combw_kernel<<<88, 256, 0, stream>>>(partial, md, W);
  topk_kernel<<<8, 64, 0, stream>>>(partial, out);
  map_kernel<<<8 * 448, 256, 0, stream>>>(md, W, out + 8);
}

// Round 22
// 238.299 us; speedup vs baseline: 1.0622x; 1.0622x over previous
//
#include <hip/hip_runtime.h>
#include <hip/hip_bf16.h>

#define NROW_F 8192
#define NROW_B 65536
#define KDIM   384
#define BM 128
#define BN 128
#define NSUB 16
#define NGRP (NROW_B / (BN * NSUB))      // 32
#define NBM  (NROW_F / BM)               // 64
#define NWG  (NBM * NGRP)                // 2048

// LDS (80 KB -> 2 blocks/CU):
//   [0,48K)  A staging (prologue only). After A->regs: sB [0,8K),
//            red [16K,17K), B bufs 4,5 [24K,40K).
//   [48K,80K) B bufs 0..3.
#define LDSS2 0
#define LDSR2 16384
#define BBASE(i) ((i) < 4 ? 49152 + 8192 * (i) : 24576 + 8192 * ((i) - 4))
#define LDS_TOT 81920

typedef int   i32x4 __attribute__((ext_vector_type(4)));
typedef float f32x4 __attribute__((ext_vector_type(4)));

static __device__ __forceinline__ void stage16(const void* g, void* l) {
  __builtin_amdgcn_global_load_lds(
      (const __attribute__((address_space(1))) unsigned int*)g,
      (__attribute__((address_space(3))) unsigned int*)l, 16, 0, 0);
}

// ---------------------------------------------------------------------------
// 1) L2-normalize rows + symmetric i8 quantization with per-row scale.
// ---------------------------------------------------------------------------
__global__ __launch_bounds__(256) void quantize_rows_kernel(
    const float* __restrict__ in, char* __restrict__ out8,
    float* __restrict__ scales, int nrows) {
  int row = blockIdx.x * 8 + (threadIdx.x >> 5);
  int l   = threadIdx.x & 31;
  if (row >= nrows) return;
  const f32x4* r = (const f32x4*)(in + (size_t)row * KDIM);
  f32x4 v[3];
  float ss = 0.f, mx = 0.f;
#pragma unroll
  for (int i = 0; i < 3; ++i) {
    v[i] = r[l + i * 32];
#pragma unroll
    for (int j = 0; j < 4; ++j) {
      ss += v[i][j] * v[i][j];
      mx = fmaxf(mx, fabsf(v[i][j]));
    }
  }
#pragma unroll
  for (int d = 1; d < 32; d <<= 1) {
    ss += __shfl_xor(ss, d, 64);
    mx = fmaxf(mx, __shfl_xor(mx, d, 64));
  }
  mx = fmaxf(mx, 1e-30f);
  float inv = rsqrtf(fmaxf(ss, 1e-24f));
  float scl = 127.0f / mx;
  if (l == 0) scales[row] = mx * inv * (1.0f / 127.0f);
  char* o = out8 + (size_t)row * KDIM;
#pragma unroll
  for (int i = 0; i < 3; ++i) {
    char4 c;
    c.x = (char)__float2int_rn(v[i][0] * scl);
    c.y = (char)__float2int_rn(v[i][1] * scl);
    c.z = (char)__float2int_rn(v[i][2] * scl);
    c.w = (char)__float2int_rn(v[i][3] * scl);
    *(char4*)(o + (l + i * 32) * 4) = c;
  }
}

// ---------------------------------------------------------------------------
// 2) maxsim: i8 MFMA 16x16x64, A in regs, K=128 per phase (48 phases halve
//    sync vs r19's 96). B six-buffered. RACE FIX vs r21: phase p stages into
//    bufs ((2p+4)%6,(2p+5)%6) — the pair whose ds_reads completed LAST phase
//    (each wave's lgkm(0) precedes the phase-top barrier), never the pair
//    being read this phase (r21 let a fast wave's DMA land in a buffer a
//    slow wave was still ds_reading).
//    Stage koffs: p=0 -> (4,5)@s ; p=1 -> (0,1)@s+1 ; p=2 -> (2,3)@s+1.
//    Prefetch distance 2 phases (~1600cy > HBM 900cy). Uniform vmcnt(4):
//    prologue = sB + bufs0..3 (10 outstanding); every phase-top retires
//    exactly the pair staged 2 phases earlier.
// ---------------------------------------------------------------------------
__global__ __launch_bounds__(256, 2) void maxsim_kernel(
    const char* __restrict__ F8,    // 8192 x 384 i8
    const char* __restrict__ B8,    // 65536 x 384 i8
    const float* __restrict__ sA,   // 8192
    const float* __restrict__ sB,   // 65536
    float* __restrict__ partial) {  // NGRP x 8192 (max sim)
  __shared__ __align__(16) char smem[LDS_TOT];

  const int tid  = threadIdx.x;
  const int wv   = tid >> 6;         // 0..3
  const int lane = tid & 63;
  const int l15  = lane & 15;
  const int lhi  = lane >> 4;
  const int wr   = wv >> 1;          // 0..1 (row half)
  const int wc   = wv & 1;           // 0..1 (col half)

  const int wg  = (blockIdx.x & 7) * (NWG / 8) + (blockIdx.x >> 3);
  const int bm  = wg & (NBM - 1);
  const int grp = wg >> 6;
  const size_t brow = (size_t)bm * BM;

  const int srow = tid >> 2;                           // 0..63
  const int gsw  = (tid & 3) ^ ((tid >> 3) & 3);       // inverse write swizzle

  // ---- prologue step 1: stage A (12 issues), drain, A -> registers ----
  {
    const char* gA = F8 + (size_t)(brow + srow) * KDIM + gsw * 16;
    char* lA = smem + wv * 1024;
#pragma unroll
    for (int kt = 0; kt < 6; ++kt) {
      stage16(gA + kt * 64,             lA + kt * 8192);
      stage16(gA + kt * 64 + 64 * KDIM, lA + kt * 8192 + 4096);
    }
  }
  asm volatile("s_waitcnt vmcnt(0)" ::: "memory");
  __builtin_amdgcn_s_barrier();

  const int cof = ((l15 >> 1) & 3) << 4;
  auto ldA8 = [&](int k6, int m) -> i32x4 {
    int byte = k6 * 8192 + (wr * 64 + m * 16 + l15) * 64 + ((lhi << 4) ^ cof);
    return *reinterpret_cast<const i32x4*>(smem + byte);
  };
  i32x4 a[6][4];
#pragma unroll
  for (int k6 = 0; k6 < 6; ++k6)
#pragma unroll
    for (int m = 0; m < 4; ++m) a[k6][m] = ldA8(k6, m);
  asm volatile("s_waitcnt lgkmcnt(0)" ::: "memory");
  __builtin_amdgcn_s_barrier();   // ALL waves done reading A region

  // ---- prologue step 2: sB into dead A region, then bufs 0..3 ONLY ----
  {
    const char* gs = (const char*)(sB + (size_t)grp * 2048) + tid * 16;
    stage16(gs,        smem + LDSS2 + wv * 1024);
    stage16(gs + 4096, smem + LDSS2 + 4096 + wv * 1024);
  }
  auto stageB = [&](int s2, int koff, int base) {
    const char* g = B8 + ((size_t)grp * 2048 + s2 * 128 + srow) * KDIM
                    + koff * 64 + gsw * 16;
    char* l = smem + base + wv * 1024;
    stage16(g, l);
    stage16(g + (size_t)64 * KDIM, l + 4096);
  };
  stageB(0, 0, BBASE(0));
  stageB(0, 1, BBASE(1));
  stageB(0, 2, BBASE(2));
  stageB(0, 3, BBASE(3));

  auto ldB8 = [&](int base, int n) -> i32x4 {
    int byte = base + (wc * 64 + n * 16 + l15) * 64 + ((lhi << 4) ^ cof);
    return *reinterpret_cast<const i32x4*>(smem + byte);
  };

  i32x4 acc[4][4];
  f32x4 vm[4];
#pragma unroll
  for (int m = 0; m < 4; ++m) {
    vm[m] = f32x4{-1e30f, -1e30f, -1e30f, -1e30f};
#pragma unroll
    for (int n = 0; n < 4; ++n) acc[m][n] = i32x4{0, 0, 0, 0};
  }
  // entering loop: outstanding = sB(2) + bufs0..3(8) = 10.

// Phase PH (0,1,2) of subtile SUBX:
//   vmcnt(4) [pair staged 2 phases ago landed; ph0 also retires sB] -> bar
//   -> 8 ds_reads (bufs 2PH,2PH+1) -> stage pair (2PH+4)%6 (read last phase)
//   -> lgkm(4) -> 16 MFMA(a[2PH]) -> lgkm(0) -> 16 MFMA(a[2PH+1]).
#define PHASE(PH, SUBX) do {                                                  \
    asm volatile("s_waitcnt vmcnt(4)" ::: "memory");                          \
    __builtin_amdgcn_s_barrier();                                             \
    __builtin_amdgcn_sched_barrier(0);                                        \
    i32x4 b0[4], b1[4];                                                       \
    _Pragma("unroll")                                                         \
    for (int n = 0; n < 4; ++n) b0[n] = ldB8(BBASE(2 * (PH)), n);             \
    _Pragma("unroll")                                                         \
    for (int n = 0; n < 4; ++n) b1[n] = ldB8(BBASE(2 * (PH) + 1), n);         \
    {                                                                         \
      const int sx = ((PH) == 0) ? (SUBX) : (((SUBX) + 1) & (NSUB - 1));      \
      stageB(sx, (2 * (PH) + 4) % 6, BBASE((2 * (PH) + 4) % 6));              \
      stageB(sx, (2 * (PH) + 5) % 6, BBASE((2 * (PH) + 5) % 6));              \
    }                                                                         \
    asm volatile("s_waitcnt lgkmcnt(4)" ::: "memory"); /* b0 landed */        \
    __builtin_amdgcn_sched_barrier(0);                                        \
    __builtin_amdgcn_s_setprio(1);                                            \
    _Pragma("unroll")                                                         \
    for (int n = 0; n < 4; ++n)                                               \
      _Pragma("unroll")                                                       \
      for (int m = 0; m < 4; ++m)                                             \
        acc[m][n] = __builtin_amdgcn_mfma_i32_16x16x64_i8(                    \
            a[2 * (PH)][m], b0[n], acc[m][n], 0, 0, 0);                       \
    asm volatile("s_waitcnt lgkmcnt(0)" ::: "memory"); /* b1 landed */        \
    __builtin_amdgcn_sched_barrier(0);                                        \
    _Pragma("unroll")                                                         \
    for (int n = 0; n < 4; ++n)                                               \
      _Pragma("unroll")                                                       \
      for (int m = 0; m < 4; ++m)                                             \
        acc[m][n] = __builtin_amdgcn_mfma_i32_16x16x64_i8(                    \
            a[2 * (PH) + 1][m], b1[n], acc[m][n], 0, 0, 0);                   \
    __builtin_amdgcn_s_setprio(0);                                            \
  } while (0)

#define FOLD(S) do {                                                          \
    float sb[4];                                                              \
    _Pragma("unroll")                                                         \
    for (int n = 0; n < 4; ++n)                                               \
      sb[n] = *reinterpret_cast<const float*>(                                \
          smem + LDSS2 + ((S) * 128 + wc * 64 + n * 16 + l15) * 4);           \
    _Pragma("unroll")                                                         \
    for (int m = 0; m < 4; ++m) {                                             \
      _Pragma("unroll")                                                       \
      for (int n = 0; n < 4; ++n)                                             \
        _Pragma("unroll")                                                     \
        for (int j = 0; j < 4; ++j)                                           \
          vm[m][j] = fmaxf(vm[m][j], (float)acc[m][n][j] * sb[n]);            \
      _Pragma("unroll")                                                       \
      for (int n = 0; n < 4; ++n) acc[m][n] = i32x4{0, 0, 0, 0};              \
    }                                                                         \
  } while (0)

  for (int sub = 0; sub < NSUB; ++sub) {
    PHASE(0, sub);
    PHASE(1, sub);
    PHASE(2, sub);
    FOLD(sub);
  }
#undef PHASE
#undef FOLD

  // ---- epilogue ----
  asm volatile("s_waitcnt vmcnt(0)" ::: "memory");
#pragma unroll
  for (int d = 1; d < 16; d <<= 1)
#pragma unroll
    for (int m = 0; m < 4; ++m)
#pragma unroll
      for (int j = 0; j < 4; ++j)
        vm[m][j] = fmaxf(vm[m][j], __shfl_xor(vm[m][j], d, 64));

  float* red = (float*)(smem + LDSR2);
  __syncthreads();
  if (l15 == 0) {
#pragma unroll
    for (int m = 0; m < 4; ++m)
#pragma unroll
      for (int j = 0; j < 4; ++j)
        red[wc * 128 + wr * 64 + m * 16 + lhi * 4 + j] = vm[m][j];
  }
  __syncthreads();
  if (tid < BM) {
    float x = fmaxf(red[tid], red[128 + tid]);
    partial[(size_t)grp * NROW_F + brow + tid] = x * sA[brow + tid];
  }
}

// ---------------------------------------------------------------------------
// 3) combine (blocks 0..31) + build W (blocks 32..87) fused.
// ---------------------------------------------------------------------------
__global__ __launch_bounds__(256) void combw_kernel(
    const float* __restrict__ partial, float* __restrict__ md,
    float* __restrict__ W) {
  if (blockIdx.x < 32) {
    int r = blockIdx.x * 256 + threadIdx.x;
    float m = -1e30f;
#pragma unroll
    for (int c = 0; c < NGRP; ++c) m = fmaxf(m, partial[(size_t)c * NROW_F + r]);
    float d = 1.0f - m;
    md[r] = fminf(fmaxf(d, 0.0f), 2.0f);
    return;
  }
  int idx = (blockIdx.x - 32) * 256 + threadIdx.x;   // < 448*32 = 14336
  int y = idx >> 5, g = idx & 31;
  float ksum = 0.f, acc = 0.f;
#pragma unroll
  for (int t = -16; t <= 16; ++t) {
    float ft = (float)t * 0.25f;
    float kv = expf(-0.5f * ft * ft);
    ksum += kv;
    int p = y + t;
    p = (p < 0) ? -p : ((p > 447) ? 894 - p : p);
    float src = ((float)p + 0.5f) * (1.0f / 14.0f) - 0.5f;
    float fl = floorf(src);
    int i0 = (int)fl;
    float fr = src - fl;
    int c0 = i0 < 0 ? 0 : (i0 > 31 ? 31 : i0);
    int i1 = i0 + 1;
    int c1 = i1 < 0 ? 0 : (i1 > 31 ? 31 : i1);
    float w = 0.f;
    if (c0 == g) w += 1.0f - fr;
    if (c1 == g) w += fr;
    acc += kv * w;
  }
  W[idx] = acc / ksum;
}

// ---------------------------------------------------------------------------
// 4) top-10 mean per batch: 1 wave, register-resident, shuffle-only.
// ---------------------------------------------------------------------------
__global__ __launch_bounds__(64) void topk_kernel(
    const float* __restrict__ partial, float* __restrict__ out) {
  int b = blockIdx.x, lane = threadIdx.x;
  float vals[16];
#pragma unroll
  for (int k = 0; k < 16; ++k) {
    int r = b * 1024 + k * 64 + lane;
    float m = -1e30f;
#pragma unroll
    for (int c = 0; c < NGRP; ++c) m = fmaxf(m, partial[(size_t)c * NROW_F + r]);
    float d = 1.0f - m;
    vals[k] = fminf(fmaxf(d, 0.0f), 2.0f);
  }
  float total = 0.f;
  for (int it = 0; it < 10; ++it) {
    float lb = vals[0]; int li = 0;
#pragma unroll
    for (int k = 1; k < 16; ++k)
      if (vals[k] > lb) { lb = vals[k]; li = k; }
    float wm = lb;
#pragma unroll
    for (int d = 1; d < 64; d <<= 1) wm = fmaxf(wm, __shfl_xor(wm, d, 64));
    unsigned long long mask = __ballot(lb == wm);
    int winner = (int)(__ffsll(mask) - 1);
    bool kill = (lane == winner);
#pragma unroll
    for (int k = 0; k < 16; ++k)
      vals[k] = (kill && k == li) ? -1e30f : vals[k];
    total += wm;
  }
  if (lane == 0) out[b] = total * 0.1f;
}

// ---------------------------------------------------------------------------
// 5) anomaly_map = W · md_grid · W^T, one block per (b, y).
// ---------------------------------------------------------------------------
__global__ __launch_bounds__(256) void map_kernel(
    const float* __restrict__ md, const float* __restrict__ W,
    float* __restrict__ out) {  // 8 x 448 x 448
  __shared__ float tmpv[32];
  int y = blockIdx.x % 448;
  int b = blockIdx.x / 448;
  int tid = threadIdx.x;
  if (tid < 32) {
    const float* w = W + y * 32;
    const float* m = md + b * 1024 + tid;
    float s = 0.f;
#pragma unroll
    for (int gy = 0; gy < 32; ++gy) s += w[gy] * m[gy * 32];
    tmpv[tid] = s;
  }
  __syncthreads();
  for (int x = tid; x < 448; x += 256) {
    const float* w = W + x * 32;
    float s = 0.f;
#pragma unroll
    for (int gx = 0; gx < 32; ++gx) s += w[gx] * tmpv[gx];
    out[(size_t)blockIdx.x * 448 + x] = s;
  }
}

// ---------------------------------------------------------------------------
extern "C" void kernel_launch(void* const* d_in, const int* in_sizes, int n_in,
                              void* d_out, int out_size, void* d_ws, size_t ws_size,
                              hipStream_t stream) {
  const float* features = (const float*)d_in[0];   // 8*1024*384
  const float* bank     = (const float*)d_in[1];   // 65536*384
  float* out = (float*)d_out;                      // [8 scores][8*448*448 map]

  char* ws = (char*)d_ws;
  char*  mb8     = ws;                              // 25,165,824 B
  char*  f8      = ws + 25165824;                   //  3,145,728 B
  float* sB      = (float*)(ws + 28311552);         //    262,144 B
  float* sA      = (float*)(ws + 28573696);         //     32,768 B
  float* partial = (float*)(ws + 28606464);         //  1,048,576 B
  float* md      = (float*)(ws + 29655040);         //     32,768 B
  float* W       = (float*)(ws + 29687808);         //     57,344 B

  quantize_rows_kernel<<<NROW_B / 8, 256, 0, stream>>>(bank, mb8, sB, NROW_B);
  quantize_rows_kernel<<<NROW_F / 8, 256, 0, stream>>>(features, f8, sA, NROW_F);
  maxsim_kernel<<<NWG, 256, 0, stream>>>(f8, mb8, sA, sB, partial);
  combw_kernel<<<88, 256, 0, stream>>>(partial, md, W);
  topk_kernel<<<8, 64, 0, stream>>>(partial, out);
  map_kernel<<<8 * 448, 256, 0, stream>>>(md, W, out + 8);
}